// Round 6
// baseline (1555.700 us; speedup 1.0000x reference)
//
#include <hip/hip_runtime.h>
#include <cstdint>
#include <cstddef>

#define NN   200000
#define HH   128
#define BB   1024
#define LL   50
#define NNZK 3200000
#define RPBK 200      // rows per bucket
#define NBK  1000     // buckets (RPBK*NBK == NN)

typedef unsigned int uint32;
typedef __attribute__((ext_vector_type(8))) short bf16x8;
typedef __attribute__((ext_vector_type(4))) float f32x4;
union U8 { uint32 u[4]; bf16x8 v; };

// ---------- bf16 pack/unpack helpers (RNE) ----------
__device__ __forceinline__ uint32 f2bf2(float a, float b){
  uint32 ua=__float_as_uint(a), ub=__float_as_uint(b);
  ua = (ua + 0x7FFFu + ((ua>>16)&1u)) >> 16;
  ub = (ub + 0x7FFFu + ((ub>>16)&1u)) >> 16;
  return ua | (ub<<16);
}
__device__ __forceinline__ float2 bf2x2f(uint32 u){
  return make_float2(__uint_as_float(u<<16), __uint_as_float(u & 0xFFFF0000u));
}

// ---------- convert items f32 -> packed bf16 ----------
__global__ void k_cvt(const float* __restrict__ x, uint32* __restrict__ o){
  const int n = NN*64;
  for(int i=blockIdx.x*blockDim.x+threadIdx.x; i<n; i+=gridDim.x*blockDim.x){
    float2 v = ((const float2*)x)[i];
    o[i] = f2bf2(v.x, v.y);
  }
}

// ---------------- CSR build ----------------
__global__ void k_count(const int* __restrict__ rows, int* __restrict__ counts){
  for(int i=blockIdx.x*blockDim.x+threadIdx.x; i<NNZK; i+=gridDim.x*blockDim.x)
    atomicAdd(&counts[rows[i]],1);
}

__global__ __launch_bounds__(1024) void k_scan1(const int* __restrict__ counts,
    int* __restrict__ incl, int* __restrict__ bsum, int n){
  __shared__ int s[1024];
  int t=threadIdx.x; int i=blockIdx.x*1024+t;
  int v=(i<n)?counts[i]:0;
  s[t]=v; __syncthreads();
  for(int off=1; off<1024; off<<=1){
    int u=(t>=off)?s[t-off]:0;
    __syncthreads();
    s[t]+=u;
    __syncthreads();
  }
  if(i<n) incl[i]=s[t];
  if(t==1023) bsum[blockIdx.x]=s[1023];
}

__global__ void k_scan2(int* bsum, int nb){
  if(blockIdx.x==0 && threadIdx.x==0){
    int run=0;
    for(int i=0;i<nb;++i){ int v=bsum[i]; bsum[i]=run; run+=v; }
  }
}

__global__ void k_scan3(const int* __restrict__ incl, const int* __restrict__ bsum,
    int* __restrict__ rp, int n){
  int i=blockIdx.x*blockDim.x+threadIdx.x;
  if(i<n){
    rp[i+1]=incl[i]+bsum[i>>10];
    if(i==0) rp[0]=0;
  }
}

// ---------------- bucketed CSR permutation (kills write amplification) ----------------
__global__ void k_binit(const int* __restrict__ rp, int* __restrict__ bcur){
  int i=blockIdx.x*blockDim.x+threadIdx.x;
  if(i<NBK) bcur[i]=rp[i*RPBK];
}

// pass 1: append (col|rowoff<<18, val) into this row-bucket's CSR region
__global__ void k_bucket_scatter(const int* __restrict__ rows, const int* __restrict__ cols,
    const float* __restrict__ vals, int* __restrict__ bcur, int2* __restrict__ bpk){
  for(int i=blockIdx.x*blockDim.x+threadIdx.x; i<NNZK; i+=gridDim.x*blockDim.x){
    int r=rows[i];
    int b=r/RPBK, ro=r-b*RPBK;
    int p=atomicAdd(&bcur[b],1);
    bpk[p]=make_int2(cols[i] | (ro<<18), __float_as_int(vals[i]));
  }
}

// pass 2: one block per bucket; per-row LDS cursors -> write pk in CSR order
__global__ __launch_bounds__(256) void k_bucket_sort(const int2* __restrict__ bpk,
    const int* __restrict__ rp, int2* __restrict__ pk){
  __shared__ int cur[RPBK];
  int b=blockIdx.x, t=threadIdx.x;
  if(t<RPBK) cur[t]=rp[b*RPBK+t];
  __syncthreads();
  int j0=rp[b*RPBK], j1=rp[(b+1)*RPBK];
  for(int j=j0+t; j<j1; j+=256){
    int2 e=bpk[j];
    int ro=((uint32)e.x)>>18;
    int col=e.x & 0x3FFFF;
    int p=atomicAdd(&cur[ro],1);
    pk[p]=make_int2(col, e.y);
  }
}

// ---------------- SpMM steps (bf16 src, one wave per row, 4x unrolled) ----------------
__global__ __launch_bounds__(256) void k_spmm_b(
    const int2* __restrict__ pk, const int* __restrict__ rp,
    const uint32* __restrict__ src, uint32* __restrict__ dst)
{
  int wid = blockIdx.x*4 + (threadIdx.x>>6);
  int lane = threadIdx.x & 63;
  if(wid>=NN) return;
  int j0=rp[wid], j1=rp[wid+1];
  float ax=0.f, ay=0.f;
  int j=j0;
  for(; j+4<=j1; j+=4){
    int2 p0=pk[j], p1=pk[j+1], p2=pk[j+2], p3=pk[j+3];
    uint32 e0=src[(size_t)p0.x*64+lane];
    uint32 e1=src[(size_t)p1.x*64+lane];
    uint32 e2=src[(size_t)p2.x*64+lane];
    uint32 e3=src[(size_t)p3.x*64+lane];
    float v0=__int_as_float(p0.y), v1=__int_as_float(p1.y);
    float v2=__int_as_float(p2.y), v3=__int_as_float(p3.y);
    float2 f0=bf2x2f(e0), f1=bf2x2f(e1), f2=bf2x2f(e2), f3=bf2x2f(e3);
    ax=fmaf(v0,f0.x,ax); ay=fmaf(v0,f0.y,ay);
    ax=fmaf(v1,f1.x,ax); ay=fmaf(v1,f1.y,ay);
    ax=fmaf(v2,f2.x,ax); ay=fmaf(v2,f2.y,ay);
    ax=fmaf(v3,f3.x,ax); ay=fmaf(v3,f3.y,ay);
  }
  for(; j<j1; ++j){
    int2 p=pk[j];
    float2 f=bf2x2f(src[(size_t)p.x*64+lane]);
    float v=__int_as_float(p.y);
    ax=fmaf(v,f.x,ax); ay=fmaf(v,f.y,ay);
  }
  dst[(size_t)wid*64+lane]=f2bf2(ax,ay);
}

// final: e3 = A@B ; acc=(x+e1+e2+e3)*0.25 -> hgout(f32, 4B-aligned) + hgbf(packed bf16)
__global__ __launch_bounds__(256) void k_spmm_final(
    const int2* __restrict__ pk, const int* __restrict__ rp,
    const uint32* __restrict__ Abuf, const uint32* __restrict__ Bbuf,
    const float* __restrict__ x, float* __restrict__ acc, uint32* __restrict__ obf)
{
  int wid = blockIdx.x*4 + (threadIdx.x>>6);
  int lane = threadIdx.x & 63;
  if(wid>=NN) return;
  int j0=rp[wid], j1=rp[wid+1];
  float ax=0.f, ay=0.f;
  int j=j0;
  for(; j+4<=j1; j+=4){
    int2 p0=pk[j], p1=pk[j+1], p2=pk[j+2], p3=pk[j+3];
    uint32 e0=Bbuf[(size_t)p0.x*64+lane];
    uint32 e1=Bbuf[(size_t)p1.x*64+lane];
    uint32 e2=Bbuf[(size_t)p2.x*64+lane];
    uint32 e3=Bbuf[(size_t)p3.x*64+lane];
    float v0=__int_as_float(p0.y), v1=__int_as_float(p1.y);
    float v2=__int_as_float(p2.y), v3=__int_as_float(p3.y);
    float2 f0=bf2x2f(e0), f1=bf2x2f(e1), f2=bf2x2f(e2), f3=bf2x2f(e3);
    ax=fmaf(v0,f0.x,ax); ay=fmaf(v0,f0.y,ay);
    ax=fmaf(v1,f1.x,ax); ay=fmaf(v1,f1.y,ay);
    ax=fmaf(v2,f2.x,ax); ay=fmaf(v2,f2.y,ay);
    ax=fmaf(v3,f3.x,ax); ay=fmaf(v3,f3.y,ay);
  }
  for(; j<j1; ++j){
    int2 p=pk[j];
    float2 f=bf2x2f(Bbuf[(size_t)p.x*64+lane]);
    float v=__int_as_float(p.y);
    ax=fmaf(v,f.x,ax); ay=fmaf(v,f.y,ay);
  }
  float2 xv = ((const float2*)x)[(size_t)wid*64+lane];
  float2 e1v = bf2x2f(Abuf[(size_t)wid*64+lane]);
  float2 e2v = bf2x2f(Bbuf[(size_t)wid*64+lane]);
  size_t ao=(size_t)wid*128 + lane*2;
  float rx = (xv.x + e1v.x + e2v.x + ax)*0.25f;
  float ry = (xv.y + e1v.y + e2v.y + ay)*0.25f;
  acc[ao]=rx; acc[ao+1]=ry;
  obf[(size_t)wid*64+lane]=f2bf2(rx,ry);
}

// ---------------- posW1[l][h] = pos_table[l]@w1_W[:128] + w1_b ----------------
__global__ __launch_bounds__(128) void k_posw1(const float* __restrict__ pos_table,
    const float* __restrict__ w1W, const float* __restrict__ w1b, float* __restrict__ posW1){
  int l=blockIdx.x, h=threadIdx.x;
  float a=w1b[h];
  for(int k=0;k<HH;++k) a = fmaf(pos_table[l*HH+k], w1W[k*HH+h], a);
  posW1[l*HH+h]=a;
}

// ---------------- MFMA GEMM 1: ns = tanh(posW1[l] + gather(hgbf) @ w1seq) ----------------
#define AS 69
#define BS 67
__global__ __launch_bounds__(256) void k_nsgemm(
    const uint32* __restrict__ hgbf, const int* __restrict__ rev,
    const float* __restrict__ w1b, const float* __restrict__ posW1,
    float* __restrict__ ns)
{
  __shared__ uint32 sA[64*AS];
  __shared__ uint32 sB[128*BS];
  const int tid=threadIdx.x;
  {
    int r=tid>>2, p=tid&3;
    int idx = rev[blockIdx.x*64 + r];
    if(idx>0 && idx<=NN){
      const uint32* s = hgbf + (size_t)(idx-1)*64 + p*16;
      #pragma unroll
      for(int j=0;j<16;++j) sA[r*AS+p*16+j]=s[j];
    } else {
      #pragma unroll
      for(int j=0;j<16;++j) sA[r*AS+p*16+j]=0u;
    }
  }
  for(int i=tid;i<128*64;i+=256){
    int n=i&127, kp=i>>7;
    sB[n*BS+kp]=f2bf2(w1b[(2*kp)*HH+n], w1b[(2*kp+1)*HH+n]);
  }
  __syncthreads();
  const int w=tid>>6, lane=tid&63, g=lane>>4, m15=lane&15;
  f32x4 acc[8];
  #pragma unroll
  for(int nt=0;nt<8;++nt) acc[nt]=(f32x4){0.f,0.f,0.f,0.f};
  #pragma unroll
  for(int kt=0;kt<4;++kt){
    U8 a;
    int ab=(w*16+m15)*AS + kt*16 + g*4;
    a.u[0]=sA[ab]; a.u[1]=sA[ab+1]; a.u[2]=sA[ab+2]; a.u[3]=sA[ab+3];
    #pragma unroll
    for(int nt=0;nt<8;++nt){
      U8 b;
      int bb=(nt*16+m15)*BS + kt*16 + g*4;
      b.u[0]=sB[bb]; b.u[1]=sB[bb+1]; b.u[2]=sB[bb+2]; b.u[3]=sB[bb+3];
      acc[nt]=__builtin_amdgcn_mfma_f32_16x16x32_bf16(a.v,b.v,acc[nt],0,0,0);
    }
  }
  int rowbase = blockIdx.x*64 + w*16 + g*4;
  #pragma unroll
  for(int r=0;r<4;++r){
    int gr=rowbase+r;
    int l=gr%LL;
    #pragma unroll
    for(int nt=0;nt<8;++nt){
      int col=nt*16+m15;
      ns[(size_t)gr*HH+col] = tanhf(acc[nt][r] + posW1[l*HH+col]);
    }
  }
}

// ---------------- MFMA GEMM 2: alpha = sum_h sigmoid(sm2[b]+ns@w3+b3)*fT ----------------
__global__ __launch_bounds__(256) void k_agemm(
    const float* __restrict__ ns, const float* __restrict__ w3,
    const float* __restrict__ sm2, const float* __restrict__ b3,
    const float* __restrict__ fT, float* __restrict__ alpha)
{
  __shared__ uint32 sA[64*AS];
  __shared__ uint32 sB[128*BS];
  const int tid=threadIdx.x;
  {
    int r=tid>>2, p=tid&3;
    const float2* s = (const float2*)(ns + (size_t)(blockIdx.x*64+r)*HH + p*32);
    #pragma unroll
    for(int j=0;j<16;++j){ float2 f=s[j]; sA[r*AS+p*16+j]=f2bf2(f.x,f.y); }
  }
  for(int i=tid;i<128*64;i+=256){
    int n=i&127, kp=i>>7;
    sB[n*BS+kp]=f2bf2(w3[(2*kp)*HH+n], w3[(2*kp+1)*HH+n]);
  }
  __syncthreads();
  const int w=tid>>6, lane=tid&63, g=lane>>4, m15=lane&15;
  f32x4 acc[8];
  #pragma unroll
  for(int nt=0;nt<8;++nt) acc[nt]=(f32x4){0.f,0.f,0.f,0.f};
  #pragma unroll
  for(int kt=0;kt<4;++kt){
    U8 a;
    int ab=(w*16+m15)*AS + kt*16 + g*4;
    a.u[0]=sA[ab]; a.u[1]=sA[ab+1]; a.u[2]=sA[ab+2]; a.u[3]=sA[ab+3];
    #pragma unroll
    for(int nt=0;nt<8;++nt){
      U8 b;
      int bb=(nt*16+m15)*BS + kt*16 + g*4;
      b.u[0]=sB[bb]; b.u[1]=sB[bb+1]; b.u[2]=sB[bb+2]; b.u[3]=sB[bb+3];
      acc[nt]=__builtin_amdgcn_mfma_f32_16x16x32_bf16(a.v,b.v,acc[nt],0,0,0);
    }
  }
  int rowbase = blockIdx.x*64 + w*16 + g*4;
  #pragma unroll
  for(int r=0;r<4;++r){
    int gr=rowbase+r;
    int b_=gr/LL;
    float rsum=0.f;
    #pragma unroll
    for(int nt=0;nt<8;++nt){
      int col=nt*16+m15;
      float gv = acc[nt][r] + sm2[b_*HH+col] + b3[col];
      rsum += fT[col] / (1.f + expf(-gv));
    }
    rsum += __shfl_xor(rsum,1);
    rsum += __shfl_xor(rsum,2);
    rsum += __shfl_xor(rsum,4);
    rsum += __shfl_xor(rsum,8);
    if(m15==0) alpha[gr]=rsum;
  }
}

// ---------------- sess_mean + sm2 ----------------
__global__ __launch_bounds__(128) void k_smean(const float* __restrict__ hgo,
    const int* __restrict__ rev, const int* __restrict__ slen, float* __restrict__ mean){
  int b=blockIdx.x, h=threadIdx.x;
  float s=0.f;
  for(int l=0;l<LL;++l){
    int idx=rev[b*LL+l];
    if(idx>0 && idx<=NN) s += hgo[(size_t)(idx-1)*HH+h];
  }
  mean[b*HH+h]=s/(float)slen[b];
}

__global__ __launch_bounds__(128) void k_sm2(const float* __restrict__ mean,
    const float* __restrict__ w2, const float* __restrict__ b2, float* __restrict__ sm2){
  __shared__ float sm[HH];
  int b=blockIdx.x, h=threadIdx.x;
  sm[h]=mean[b*HH+h]; __syncthreads();
  float a=b2[h];
  for(int k=0;k<HH;++k) a=fmaf(sm[k], w2[k*HH+h], a);
  sm2[b*HH+h]=a;
}

// ---------------- theta ----------------
__global__ __launch_bounds__(128) void k_theta(const float* __restrict__ ns,
    const float* __restrict__ alpha, float* __restrict__ hg_sess){
  __shared__ float sal[64];
  int b=blockIdx.x, h=threadIdx.x;
  if(h<LL) sal[h]=alpha[b*LL+h];
  __syncthreads();
  float t=0.f;
  for(int l=0;l<LL;++l) t=fmaf(sal[l], ns[((size_t)b*LL+l)*HH+h], t);
  hg_sess[(size_t)b*HH+h]=t;
}

// ---------------- line graph ----------------
__global__ __launch_bounds__(128) void k_sessline(const float* __restrict__ items,
    const int* __restrict__ sinfo, const int* __restrict__ slen,
    float* __restrict__ cur, float* __restrict__ acc){
  int b=blockIdx.x, h=threadIdx.x;
  float s=0.f;
  for(int l=0;l<LL;++l){
    int idx=sinfo[b*LL+l];
    if(idx>0 && idx<=NN) s += items[(size_t)(idx-1)*HH+h];
  }
  s /= (float)slen[b];
  cur[(size_t)b*HH+h]=s; acc[(size_t)b*HH+h]=s;
}

__global__ __launch_bounds__(128) void k_matpart(const float* __restrict__ M,
    const float* __restrict__ src, float* __restrict__ part){
  int rq = blockIdx.x >> 2;
  int kc = blockIdx.x & 3;
  int h = threadIdx.x;
  int r0 = rq*4;
  const float* m0 = M + (size_t)r0*BB + kc*256;
  const float* m1 = m0 + BB;
  const float* m2 = m1 + BB;
  const float* m3 = m2 + BB;
  const float* s0 = src + (size_t)kc*256*HH + h;
  float a0=0,a1=0,a2=0,a3=0;
  for(int k=0;k<256;++k){
    float s=s0[(size_t)k*HH];
    a0=fmaf(m0[k],s,a0); a1=fmaf(m1[k],s,a1);
    a2=fmaf(m2[k],s,a2); a3=fmaf(m3[k],s,a3);
  }
  size_t o=(size_t)kc*BB*HH + (size_t)r0*HH + h;
  part[o]=a0; part[o+HH]=a1; part[o+2*HH]=a2; part[o+3*HH]=a3;
}

__global__ __launch_bounds__(256) void k_matcomb(const float* __restrict__ part,
    float* __restrict__ dst, float* __restrict__ acc, int mode){
  int i = blockIdx.x*256+threadIdx.x;
  const int S = BB*HH;
  float v = ((part[i] + part[i+S]) + part[i+2*S]) + part[i+3*S];
  dst[i]=v;
  if(mode==1) acc[i]+=v;
  else if(mode==2) acc[i]=(acc[i]+v)*0.25f;
}

// ---------------- SSL loss (deterministic two-stage) ----------------
__global__ __launch_bounds__(128) void k_ssl(const float* __restrict__ hg,
    const float* __restrict__ line, const int* __restrict__ pr,
    const int* __restrict__ pc, float* __restrict__ part){
  int b=blockIdx.x, h=threadIdx.x;
  __shared__ float sp[2][2];
  float lv = line[(size_t)b*HH+h];
  float v1 = hg[(size_t)b*HH+h]*lv;
  float v2 = hg[(size_t)pr[b]*HH + pc[h]]*lv;
  for(int o=32;o>0;o>>=1){ v1+=__shfl_xor(v1,o); v2+=__shfl_xor(v2,o); }
  int wv=h>>6, ln=h&63;
  if(ln==0){ sp[0][wv]=v1; sp[1][wv]=v2; }
  __syncthreads();
  if(h==0){
    float pos=sp[0][0]+sp[0][1];
    float neg=sp[1][0]+sp[1][1];
    float sigp=1.f/(1.f+expf(-pos));
    float sign_=1.f/(1.f+expf(-neg));
    part[b] = -logf(1e-8f+sigp) - logf(1e-8f+(1.f-sign_));
  }
}

__global__ __launch_bounds__(256) void k_red(const float* __restrict__ part, float* __restrict__ loss){
  __shared__ float s[256];
  int t=threadIdx.x;
  s[t]=part[t]+part[t+256]+part[t+512]+part[t+768];
  __syncthreads();
  for(int o=128;o>0;o>>=1){ if(t<o) s[t]+=s[t+o]; __syncthreads(); }
  if(t==0) *loss = 0.01f*s[0];
}

extern "C" void kernel_launch(void* const* d_in, const int* in_sizes, int n_in,
                              void* d_out, int out_size, void* d_ws, size_t ws_size,
                              hipStream_t stream){
  const float* items    =(const float*)d_in[0];
  const float* pos_table=(const float*)d_in[1];
  const float* w1W      =(const float*)d_in[2];
  const float* w1b_     =(const float*)d_in[3];
  const float* w2W      =(const float*)d_in[4];
  const float* w2b      =(const float*)d_in[5];
  const float* w3W      =(const float*)d_in[6];
  const float* w3b      =(const float*)d_in[7];
  const float* fT       =(const float*)d_in[8];
  const float* hvals    =(const float*)d_in[9];
  const float* lineA    =(const float*)d_in[10];
  const float* degD     =(const float*)d_in[11];
  const int*   hrows    =(const int*)d_in[12];
  const int*   hcols    =(const int*)d_in[13];
  const int*   sinfo    =(const int*)d_in[14];   // int64 in ref -> int32 in harness
  const int*   rinfo    =(const int*)d_in[15];
  const int*   slen     =(const int*)d_in[16];
  const int*   prow     =(const int*)d_in[18];
  const int*   pcol     =(const int*)d_in[19];

  float* outf   = (float*)d_out;
  float* hg_sess= outf;
  float* loss   = outf + (size_t)BB*HH;
  float* hgout  = outf + (size_t)BB*HH + 1;    // hg_item (4B-aligned only)

  char* base=(char*)d_ws; size_t off=0;
  auto carve=[&](size_t bytes)->char*{ char* p=base+off; off=(off+bytes+255)&~(size_t)255; return p; };

  float*  posW1 =(float*) carve((size_t)LL*HH*4);
  float*  curA  =(float*) carve((size_t)BB*HH*4);
  float*  curB  =(float*) carve((size_t)BB*HH*4);
  float*  tmpv  =(float*) carve((size_t)BB*HH*4);
  float*  accL  =(float*) carve((size_t)BB*HH*4);
  float*  lpart =(float*) carve((size_t)BB*4);
  float*  mpart =(float*) carve((size_t)4*BB*HH*4);
  int2*   pk    =(int2*)  carve((size_t)NNZK*8);
  int*    counts=(int*)   carve((size_t)NN*4);
  int*    incl  =(int*)   carve((size_t)NN*4);
  int*    bsum  =(int*)   carve(1024);
  int*    rp    =(int*)   carve((size_t)(NN+1)*4);
  int*    bcur  =(int*)   carve((size_t)NBK*4);
  uint32* itbf  =(uint32*)carve((size_t)NN*64*4);
  uint32* A     =(uint32*)carve((size_t)NN*64*4);
  uint32* Bb    =(uint32*)carve((size_t)NN*64*4);
  if(off > ws_size) return;

  // overlays: bpk lives in A's region during CSR build (A written later);
  // after k_spmm_final: itbf -> hgbf, A -> ns, Bb -> alpha/mean/sm2
  int2*   bpk   = (int2*)A;
  uint32* hgbf  = itbf;
  float*  ns    = (float*)A;
  float*  alpha = (float*)Bb;
  float*  mean  = alpha + (size_t)BB*LL;
  float*  sm2   = mean  + (size_t)BB*HH;

  // items -> packed bf16
  k_cvt<<<2048,256,0,stream>>>(items, itbf);

  // CSR build: counts -> rp, then bucketed two-phase permutation
  hipMemsetAsync(counts,0,(size_t)NN*4,stream);
  k_count<<<2048,256,0,stream>>>(hrows,counts);
  int nb=(NN+1023)/1024;
  k_scan1<<<nb,1024,0,stream>>>(counts,incl,bsum,NN);
  k_scan2<<<1,64,0,stream>>>(bsum,nb);
  k_scan3<<<(NN+255)/256,256,0,stream>>>(incl,bsum,rp,NN);
  k_binit<<<(NBK+255)/256,256,0,stream>>>(rp,bcur);
  k_bucket_scatter<<<2048,256,0,stream>>>(hrows,hcols,hvals,bcur,bpk);
  k_bucket_sort<<<NBK,256,0,stream>>>(bpk,rp,pk);

  // hypergraph conv
  k_spmm_b    <<<NN/4,256,0,stream>>>(pk,rp, itbf, A);
  k_spmm_b    <<<NN/4,256,0,stream>>>(pk,rp, A,    Bb);
  k_spmm_final<<<NN/4,256,0,stream>>>(pk,rp, A, Bb, items, hgout, hgbf);

  // session attention (MFMA pipeline)
  k_posw1 <<<LL,HH,0,stream>>>(pos_table,w1W,w1b_,posW1);
  k_smean <<<BB,HH,0,stream>>>(hgout,rinfo,slen,mean);
  k_sm2   <<<BB,HH,0,stream>>>(mean,w2W,w2b,sm2);
  k_nsgemm<<<(BB*LL)/64,256,0,stream>>>(hgbf,rinfo,w1W+HH*HH,posW1,ns);
  k_agemm <<<(BB*LL)/64,256,0,stream>>>(ns,w3W,sm2,w3b,fT,alpha);
  k_theta <<<BB,HH,0,stream>>>(ns,alpha,hg_sess);

  // line graph conv
  k_sessline<<<BB,HH,0,stream>>>(items,sinfo,slen,curA,accL);
  for(int s=0;s<3;++s){
    float* srcv=(s&1)?curB:curA;
    float* dstv=(s&1)?curA:curB;
    k_matpart<<<BB,128,0,stream>>>(lineA,srcv,mpart);
    k_matcomb<<<BB*HH/256,256,0,stream>>>(mpart,tmpv,nullptr,0);
    k_matpart<<<BB,128,0,stream>>>(degD,tmpv,mpart);
    k_matcomb<<<BB*HH/256,256,0,stream>>>(mpart,dstv,accL,(s==2)?2:1);
  }

  // SSL loss
  k_ssl<<<BB,HH,0,stream>>>(hg_sess,accL,prow,pcol,lpart);
  k_red<<<1,256,0,stream>>>(lpart,loss);
}

// Round 7
// 1002.404 us; speedup vs baseline: 1.5520x; 1.5520x over previous
//
#include <hip/hip_runtime.h>
#include <cstdint>
#include <cstddef>

#define NN   200000
#define HH   128
#define BB   1024
#define LL   50
#define NNZK 3200000
#define RPBK 200      // rows per bucket
#define NBK  1000     // buckets (RPBK*NBK == NN)
#define MSB  256      // multi-split blocks
#define CHUNK (NNZK/MSB)   // 12500 entries per block

typedef unsigned int uint32;
typedef __attribute__((ext_vector_type(8))) short bf16x8;
typedef __attribute__((ext_vector_type(4))) float f32x4;
union U8 { uint32 u[4]; bf16x8 v; };

// ---------- bf16 pack/unpack helpers (RNE) ----------
__device__ __forceinline__ uint32 f2bf2(float a, float b){
  uint32 ua=__float_as_uint(a), ub=__float_as_uint(b);
  ua = (ua + 0x7FFFu + ((ua>>16)&1u)) >> 16;
  ub = (ub + 0x7FFFu + ((ub>>16)&1u)) >> 16;
  return ua | (ub<<16);
}
__device__ __forceinline__ float2 bf2x2f(uint32 u){
  return make_float2(__uint_as_float(u<<16), __uint_as_float(u & 0xFFFF0000u));
}

// ---------- convert items f32 -> packed bf16 ----------
__global__ void k_cvt(const float* __restrict__ x, uint32* __restrict__ o){
  const int n = NN*64;
  for(int i=blockIdx.x*blockDim.x+threadIdx.x; i<n; i+=gridDim.x*blockDim.x){
    float2 v = ((const float2*)x)[i];
    o[i] = f2bf2(v.x, v.y);
  }
}

// ---------------- CSR build ----------------
__global__ void k_count(const int* __restrict__ rows, int* __restrict__ counts){
  for(int i=blockIdx.x*blockDim.x+threadIdx.x; i<NNZK; i+=gridDim.x*blockDim.x)
    atomicAdd(&counts[rows[i]],1);
}

__global__ __launch_bounds__(1024) void k_scan1(const int* __restrict__ counts,
    int* __restrict__ incl, int* __restrict__ bsum, int n){
  __shared__ int s[1024];
  int t=threadIdx.x; int i=blockIdx.x*1024+t;
  int v=(i<n)?counts[i]:0;
  s[t]=v; __syncthreads();
  for(int off=1; off<1024; off<<=1){
    int u=(t>=off)?s[t-off]:0;
    __syncthreads();
    s[t]+=u;
    __syncthreads();
  }
  if(i<n) incl[i]=s[t];
  if(t==1023) bsum[blockIdx.x]=s[1023];
}

__global__ void k_scan2(int* bsum, int nb){
  if(blockIdx.x==0 && threadIdx.x==0){
    int run=0;
    for(int i=0;i<nb;++i){ int v=bsum[i]; bsum[i]=run; run+=v; }
  }
}

__global__ void k_scan3(const int* __restrict__ incl, const int* __restrict__ bsum,
    int* __restrict__ rp, int n){
  int i=blockIdx.x*blockDim.x+threadIdx.x;
  if(i<n){
    rp[i+1]=incl[i]+bsum[i>>10];
    if(i==0) rp[0]=0;
  }
}

// ---------------- block-level multi-split (low-contention, block-owned writes) ----------------
__global__ void k_binit(const int* __restrict__ rp, int* __restrict__ bcur){
  int i=blockIdx.x*blockDim.x+threadIdx.x;
  if(i<NBK) bcur[i]=rp[i*RPBK];
}

// two-pass per block: LDS histogram -> one global atomic per (block,bucket) -> ranged writes
__global__ __launch_bounds__(256) void k_msplit(const int* __restrict__ rows,
    const int* __restrict__ cols, const float* __restrict__ vals,
    int* __restrict__ bcur, int2* __restrict__ bpk){
  __shared__ int hist[NBK];
  __shared__ int rbase[NBK];
  const int tid=threadIdx.x;
  const int i0=blockIdx.x*CHUNK, i1=i0+CHUNK;
  for(int b=tid;b<NBK;b+=256) hist[b]=0;
  __syncthreads();
  for(int i=i0+tid;i<i1;i+=256) atomicAdd(&hist[rows[i]/RPBK],1);
  __syncthreads();
  for(int b=tid;b<NBK;b+=256){
    int c=hist[b];
    rbase[b] = c ? atomicAdd(&bcur[b],c) : 0;
  }
  __syncthreads();
  for(int b=tid;b<NBK;b+=256) hist[b]=0;
  __syncthreads();
  for(int i=i0+tid;i<i1;i+=256){
    int r=rows[i];
    int b=r/RPBK, ro=r-b*RPBK;
    int p = rbase[b] + atomicAdd(&hist[b],1);
    bpk[p]=make_int2(cols[i] | (ro<<18), __float_as_int(vals[i]));
  }
}

// pass 2: one block per bucket; per-row LDS cursors -> write pk in CSR order
__global__ __launch_bounds__(256) void k_bucket_sort(const int2* __restrict__ bpk,
    const int* __restrict__ rp, int2* __restrict__ pk){
  __shared__ int cur[RPBK];
  int b=blockIdx.x, t=threadIdx.x;
  if(t<RPBK) cur[t]=rp[b*RPBK+t];
  __syncthreads();
  int j0=rp[b*RPBK], j1=rp[(b+1)*RPBK];
  for(int j=j0+t; j<j1; j+=256){
    int2 e=bpk[j];
    int ro=((uint32)e.x)>>18;
    int col=e.x & 0x3FFFF;
    int p=atomicAdd(&cur[ro],1);
    pk[p]=make_int2(col, e.y);
  }
}

// ---------------- SpMM steps (bf16 src, one wave per row, 4x unrolled) ----------------
__global__ __launch_bounds__(256) void k_spmm_b(
    const int2* __restrict__ pk, const int* __restrict__ rp,
    const uint32* __restrict__ src, uint32* __restrict__ dst)
{
  int wid = blockIdx.x*4 + (threadIdx.x>>6);
  int lane = threadIdx.x & 63;
  if(wid>=NN) return;
  int j0=rp[wid], j1=rp[wid+1];
  float ax=0.f, ay=0.f;
  int j=j0;
  for(; j+4<=j1; j+=4){
    int2 p0=pk[j], p1=pk[j+1], p2=pk[j+2], p3=pk[j+3];
    uint32 e0=src[(size_t)p0.x*64+lane];
    uint32 e1=src[(size_t)p1.x*64+lane];
    uint32 e2=src[(size_t)p2.x*64+lane];
    uint32 e3=src[(size_t)p3.x*64+lane];
    float v0=__int_as_float(p0.y), v1=__int_as_float(p1.y);
    float v2=__int_as_float(p2.y), v3=__int_as_float(p3.y);
    float2 f0=bf2x2f(e0), f1=bf2x2f(e1), f2=bf2x2f(e2), f3=bf2x2f(e3);
    ax=fmaf(v0,f0.x,ax); ay=fmaf(v0,f0.y,ay);
    ax=fmaf(v1,f1.x,ax); ay=fmaf(v1,f1.y,ay);
    ax=fmaf(v2,f2.x,ax); ay=fmaf(v2,f2.y,ay);
    ax=fmaf(v3,f3.x,ax); ay=fmaf(v3,f3.y,ay);
  }
  for(; j<j1; ++j){
    int2 p=pk[j];
    float2 f=bf2x2f(src[(size_t)p.x*64+lane]);
    float v=__int_as_float(p.y);
    ax=fmaf(v,f.x,ax); ay=fmaf(v,f.y,ay);
  }
  dst[(size_t)wid*64+lane]=f2bf2(ax,ay);
}

// final: e3 = A@B ; acc=(x+e1+e2+e3)*0.25 -> hgout(f32, 4B-aligned) + hgbf(packed bf16)
__global__ __launch_bounds__(256) void k_spmm_final(
    const int2* __restrict__ pk, const int* __restrict__ rp,
    const uint32* __restrict__ Abuf, const uint32* __restrict__ Bbuf,
    const float* __restrict__ x, float* __restrict__ acc, uint32* __restrict__ obf)
{
  int wid = blockIdx.x*4 + (threadIdx.x>>6);
  int lane = threadIdx.x & 63;
  if(wid>=NN) return;
  int j0=rp[wid], j1=rp[wid+1];
  float ax=0.f, ay=0.f;
  int j=j0;
  for(; j+4<=j1; j+=4){
    int2 p0=pk[j], p1=pk[j+1], p2=pk[j+2], p3=pk[j+3];
    uint32 e0=Bbuf[(size_t)p0.x*64+lane];
    uint32 e1=Bbuf[(size_t)p1.x*64+lane];
    uint32 e2=Bbuf[(size_t)p2.x*64+lane];
    uint32 e3=Bbuf[(size_t)p3.x*64+lane];
    float v0=__int_as_float(p0.y), v1=__int_as_float(p1.y);
    float v2=__int_as_float(p2.y), v3=__int_as_float(p3.y);
    float2 f0=bf2x2f(e0), f1=bf2x2f(e1), f2=bf2x2f(e2), f3=bf2x2f(e3);
    ax=fmaf(v0,f0.x,ax); ay=fmaf(v0,f0.y,ay);
    ax=fmaf(v1,f1.x,ax); ay=fmaf(v1,f1.y,ay);
    ax=fmaf(v2,f2.x,ax); ay=fmaf(v2,f2.y,ay);
    ax=fmaf(v3,f3.x,ax); ay=fmaf(v3,f3.y,ay);
  }
  for(; j<j1; ++j){
    int2 p=pk[j];
    float2 f=bf2x2f(Bbuf[(size_t)p.x*64+lane]);
    float v=__int_as_float(p.y);
    ax=fmaf(v,f.x,ax); ay=fmaf(v,f.y,ay);
  }
  float2 xv = ((const float2*)x)[(size_t)wid*64+lane];
  float2 e1v = bf2x2f(Abuf[(size_t)wid*64+lane]);
  float2 e2v = bf2x2f(Bbuf[(size_t)wid*64+lane]);
  size_t ao=(size_t)wid*128 + lane*2;
  float rx = (xv.x + e1v.x + e2v.x + ax)*0.25f;
  float ry = (xv.y + e1v.y + e2v.y + ay)*0.25f;
  acc[ao]=rx; acc[ao+1]=ry;
  obf[(size_t)wid*64+lane]=f2bf2(rx,ry);
}

// ---------------- posW1[l][h] = pos_table[l]@w1_W[:128] + w1_b ----------------
__global__ __launch_bounds__(128) void k_posw1(const float* __restrict__ pos_table,
    const float* __restrict__ w1W, const float* __restrict__ w1b, float* __restrict__ posW1){
  int l=blockIdx.x, h=threadIdx.x;
  float a=w1b[h];
  for(int k=0;k<HH;++k) a = fmaf(pos_table[l*HH+k], w1W[k*HH+h], a);
  posW1[l*HH+h]=a;
}

// ---------------- MFMA GEMM 1: ns = tanh(posW1[l] + gather(hgbf) @ w1seq) ----------------
#define AS 69
#define BS 67
__global__ __launch_bounds__(256) void k_nsgemm(
    const uint32* __restrict__ hgbf, const int* __restrict__ rev,
    const float* __restrict__ w1b, const float* __restrict__ posW1,
    float* __restrict__ ns)
{
  __shared__ uint32 sA[64*AS];
  __shared__ uint32 sB[128*BS];
  const int tid=threadIdx.x;
  {
    int r=tid>>2, p=tid&3;
    int idx = rev[blockIdx.x*64 + r];
    if(idx>0 && idx<=NN){
      const uint32* s = hgbf + (size_t)(idx-1)*64 + p*16;
      #pragma unroll
      for(int j=0;j<16;++j) sA[r*AS+p*16+j]=s[j];
    } else {
      #pragma unroll
      for(int j=0;j<16;++j) sA[r*AS+p*16+j]=0u;
    }
  }
  for(int i=tid;i<128*64;i+=256){
    int n=i&127, kp=i>>7;
    sB[n*BS+kp]=f2bf2(w1b[(2*kp)*HH+n], w1b[(2*kp+1)*HH+n]);
  }
  __syncthreads();
  const int w=tid>>6, lane=tid&63, g=lane>>4, m15=lane&15;
  f32x4 acc[8];
  #pragma unroll
  for(int nt=0;nt<8;++nt) acc[nt]=(f32x4){0.f,0.f,0.f,0.f};
  #pragma unroll
  for(int kt=0;kt<4;++kt){
    U8 a;
    int ab=(w*16+m15)*AS + kt*16 + g*4;
    a.u[0]=sA[ab]; a.u[1]=sA[ab+1]; a.u[2]=sA[ab+2]; a.u[3]=sA[ab+3];
    #pragma unroll
    for(int nt=0;nt<8;++nt){
      U8 b;
      int bb=(nt*16+m15)*BS + kt*16 + g*4;
      b.u[0]=sB[bb]; b.u[1]=sB[bb+1]; b.u[2]=sB[bb+2]; b.u[3]=sB[bb+3];
      acc[nt]=__builtin_amdgcn_mfma_f32_16x16x32_bf16(a.v,b.v,acc[nt],0,0,0);
    }
  }
  int rowbase = blockIdx.x*64 + w*16 + g*4;
  #pragma unroll
  for(int r=0;r<4;++r){
    int gr=rowbase+r;
    int l=gr%LL;
    #pragma unroll
    for(int nt=0;nt<8;++nt){
      int col=nt*16+m15;
      ns[(size_t)gr*HH+col] = tanhf(acc[nt][r] + posW1[l*HH+col]);
    }
  }
}

// ---------------- MFMA GEMM 2: alpha = sum_h sigmoid(sm2[b]+ns@w3+b3)*fT ----------------
__global__ __launch_bounds__(256) void k_agemm(
    const float* __restrict__ ns, const float* __restrict__ w3,
    const float* __restrict__ sm2, const float* __restrict__ b3,
    const float* __restrict__ fT, float* __restrict__ alpha)
{
  __shared__ uint32 sA[64*AS];
  __shared__ uint32 sB[128*BS];
  const int tid=threadIdx.x;
  {
    int r=tid>>2, p=tid&3;
    const float2* s = (const float2*)(ns + (size_t)(blockIdx.x*64+r)*HH + p*32);
    #pragma unroll
    for(int j=0;j<16;++j){ float2 f=s[j]; sA[r*AS+p*16+j]=f2bf2(f.x,f.y); }
  }
  for(int i=tid;i<128*64;i+=256){
    int n=i&127, kp=i>>7;
    sB[n*BS+kp]=f2bf2(w3[(2*kp)*HH+n], w3[(2*kp+1)*HH+n]);
  }
  __syncthreads();
  const int w=tid>>6, lane=tid&63, g=lane>>4, m15=lane&15;
  f32x4 acc[8];
  #pragma unroll
  for(int nt=0;nt<8;++nt) acc[nt]=(f32x4){0.f,0.f,0.f,0.f};
  #pragma unroll
  for(int kt=0;kt<4;++kt){
    U8 a;
    int ab=(w*16+m15)*AS + kt*16 + g*4;
    a.u[0]=sA[ab]; a.u[1]=sA[ab+1]; a.u[2]=sA[ab+2]; a.u[3]=sA[ab+3];
    #pragma unroll
    for(int nt=0;nt<8;++nt){
      U8 b;
      int bb=(nt*16+m15)*BS + kt*16 + g*4;
      b.u[0]=sB[bb]; b.u[1]=sB[bb+1]; b.u[2]=sB[bb+2]; b.u[3]=sB[bb+3];
      acc[nt]=__builtin_amdgcn_mfma_f32_16x16x32_bf16(a.v,b.v,acc[nt],0,0,0);
    }
  }
  int rowbase = blockIdx.x*64 + w*16 + g*4;
  #pragma unroll
  for(int r=0;r<4;++r){
    int gr=rowbase+r;
    int b_=gr/LL;
    float rsum=0.f;
    #pragma unroll
    for(int nt=0;nt<8;++nt){
      int col=nt*16+m15;
      float gv = acc[nt][r] + sm2[b_*HH+col] + b3[col];
      rsum += fT[col] / (1.f + expf(-gv));
    }
    rsum += __shfl_xor(rsum,1);
    rsum += __shfl_xor(rsum,2);
    rsum += __shfl_xor(rsum,4);
    rsum += __shfl_xor(rsum,8);
    if(m15==0) alpha[gr]=rsum;
  }
}

// ---------------- sess_mean + sm2 ----------------
__global__ __launch_bounds__(128) void k_smean(const float* __restrict__ hgo,
    const int* __restrict__ rev, const int* __restrict__ slen, float* __restrict__ mean){
  int b=blockIdx.x, h=threadIdx.x;
  float s=0.f;
  for(int l=0;l<LL;++l){
    int idx=rev[b*LL+l];
    if(idx>0 && idx<=NN) s += hgo[(size_t)(idx-1)*HH+h];
  }
  mean[b*HH+h]=s/(float)slen[b];
}

__global__ __launch_bounds__(128) void k_sm2(const float* __restrict__ mean,
    const float* __restrict__ w2, const float* __restrict__ b2, float* __restrict__ sm2){
  __shared__ float sm[HH];
  int b=blockIdx.x, h=threadIdx.x;
  sm[h]=mean[b*HH+h]; __syncthreads();
  float a=b2[h];
  for(int k=0;k<HH;++k) a=fmaf(sm[k], w2[k*HH+h], a);
  sm2[b*HH+h]=a;
}

// ---------------- theta ----------------
__global__ __launch_bounds__(128) void k_theta(const float* __restrict__ ns,
    const float* __restrict__ alpha, float* __restrict__ hg_sess){
  __shared__ float sal[64];
  int b=blockIdx.x, h=threadIdx.x;
  if(h<LL) sal[h]=alpha[b*LL+h];
  __syncthreads();
  float t=0.f;
  for(int l=0;l<LL;++l) t=fmaf(sal[l], ns[((size_t)b*LL+l)*HH+h], t);
  hg_sess[(size_t)b*HH+h]=t;
}

// ---------------- line graph ----------------
__global__ __launch_bounds__(128) void k_sessline(const float* __restrict__ items,
    const int* __restrict__ sinfo, const int* __restrict__ slen,
    float* __restrict__ cur, float* __restrict__ acc){
  int b=blockIdx.x, h=threadIdx.x;
  float s=0.f;
  for(int l=0;l<LL;++l){
    int idx=sinfo[b*LL+l];
    if(idx>0 && idx<=NN) s += items[(size_t)(idx-1)*HH+h];
  }
  s /= (float)slen[b];
  cur[(size_t)b*HH+h]=s; acc[(size_t)b*HH+h]=s;
}

__global__ __launch_bounds__(128) void k_matpart(const float* __restrict__ M,
    const float* __restrict__ src, float* __restrict__ part){
  int rq = blockIdx.x >> 2;
  int kc = blockIdx.x & 3;
  int h = threadIdx.x;
  int r0 = rq*4;
  const float* m0 = M + (size_t)r0*BB + kc*256;
  const float* m1 = m0 + BB;
  const float* m2 = m1 + BB;
  const float* m3 = m2 + BB;
  const float* s0 = src + (size_t)kc*256*HH + h;
  float a0=0,a1=0,a2=0,a3=0;
  for(int k=0;k<256;++k){
    float s=s0[(size_t)k*HH];
    a0=fmaf(m0[k],s,a0); a1=fmaf(m1[k],s,a1);
    a2=fmaf(m2[k],s,a2); a3=fmaf(m3[k],s,a3);
  }
  size_t o=(size_t)kc*BB*HH + (size_t)r0*HH + h;
  part[o]=a0; part[o+HH]=a1; part[o+2*HH]=a2; part[o+3*HH]=a3;
}

__global__ __launch_bounds__(256) void k_matcomb(const float* __restrict__ part,
    float* __restrict__ dst, float* __restrict__ acc, int mode){
  int i = blockIdx.x*256+threadIdx.x;
  const int S = BB*HH;
  float v = ((part[i] + part[i+S]) + part[i+2*S]) + part[i+3*S];
  dst[i]=v;
  if(mode==1) acc[i]+=v;
  else if(mode==2) acc[i]=(acc[i]+v)*0.25f;
}

// ---------------- SSL loss (deterministic two-stage) ----------------
__global__ __launch_bounds__(128) void k_ssl(const float* __restrict__ hg,
    const float* __restrict__ line, const int* __restrict__ pr,
    const int* __restrict__ pc, float* __restrict__ part){
  int b=blockIdx.x, h=threadIdx.x;
  __shared__ float sp[2][2];
  float lv = line[(size_t)b*HH+h];
  float v1 = hg[(size_t)b*HH+h]*lv;
  float v2 = hg[(size_t)pr[b]*HH + pc[h]]*lv;
  for(int o=32;o>0;o>>=1){ v1+=__shfl_xor(v1,o); v2+=__shfl_xor(v2,o); }
  int wv=h>>6, ln=h&63;
  if(ln==0){ sp[0][wv]=v1; sp[1][wv]=v2; }
  __syncthreads();
  if(h==0){
    float pos=sp[0][0]+sp[0][1];
    float neg=sp[1][0]+sp[1][1];
    float sigp=1.f/(1.f+expf(-pos));
    float sign_=1.f/(1.f+expf(-neg));
    part[b] = -logf(1e-8f+sigp) - logf(1e-8f+(1.f-sign_));
  }
}

__global__ __launch_bounds__(256) void k_red(const float* __restrict__ part, float* __restrict__ loss){
  __shared__ float s[256];
  int t=threadIdx.x;
  s[t]=part[t]+part[t+256]+part[t+512]+part[t+768];
  __syncthreads();
  for(int o=128;o>0;o>>=1){ if(t<o) s[t]+=s[t+o]; __syncthreads(); }
  if(t==0) *loss = 0.01f*s[0];
}

extern "C" void kernel_launch(void* const* d_in, const int* in_sizes, int n_in,
                              void* d_out, int out_size, void* d_ws, size_t ws_size,
                              hipStream_t stream){
  const float* items    =(const float*)d_in[0];
  const float* pos_table=(const float*)d_in[1];
  const float* w1W      =(const float*)d_in[2];
  const float* w1b_     =(const float*)d_in[3];
  const float* w2W      =(const float*)d_in[4];
  const float* w2b      =(const float*)d_in[5];
  const float* w3W      =(const float*)d_in[6];
  const float* w3b      =(const float*)d_in[7];
  const float* fT       =(const float*)d_in[8];
  const float* hvals    =(const float*)d_in[9];
  const float* lineA    =(const float*)d_in[10];
  const float* degD     =(const float*)d_in[11];
  const int*   hrows    =(const int*)d_in[12];
  const int*   hcols    =(const int*)d_in[13];
  const int*   sinfo    =(const int*)d_in[14];   // int64 in ref -> int32 in harness
  const int*   rinfo    =(const int*)d_in[15];
  const int*   slen     =(const int*)d_in[16];
  const int*   prow     =(const int*)d_in[18];
  const int*   pcol     =(const int*)d_in[19];

  float* outf   = (float*)d_out;
  float* hg_sess= outf;
  float* loss   = outf + (size_t)BB*HH;
  float* hgout  = outf + (size_t)BB*HH + 1;    // hg_item (4B-aligned only)

  char* base=(char*)d_ws; size_t off=0;
  auto carve=[&](size_t bytes)->char*{ char* p=base+off; off=(off+bytes+255)&~(size_t)255; return p; };

  float*  posW1 =(float*) carve((size_t)LL*HH*4);
  float*  curA  =(float*) carve((size_t)BB*HH*4);
  float*  curB  =(float*) carve((size_t)BB*HH*4);
  float*  tmpv  =(float*) carve((size_t)BB*HH*4);
  float*  accL  =(float*) carve((size_t)BB*HH*4);
  float*  lpart =(float*) carve((size_t)BB*4);
  float*  mpart =(float*) carve((size_t)4*BB*HH*4);
  int2*   pk    =(int2*)  carve((size_t)NNZK*8);
  int*    counts=(int*)   carve((size_t)NN*4);
  int*    incl  =(int*)   carve((size_t)NN*4);
  int*    bsum  =(int*)   carve(1024);
  int*    rp    =(int*)   carve((size_t)(NN+1)*4);
  int*    bcur  =(int*)   carve((size_t)NBK*4);
  uint32* itbf  =(uint32*)carve((size_t)NN*64*4);
  uint32* A     =(uint32*)carve((size_t)NN*64*4);
  uint32* Bb    =(uint32*)carve((size_t)NN*64*4);
  if(off > ws_size) return;

  // overlays: bpk lives in A's region during CSR build (A written later);
  // after k_spmm_final: itbf -> hgbf, A -> ns, Bb -> alpha/mean/sm2
  int2*   bpk   = (int2*)A;
  uint32* hgbf  = itbf;
  float*  ns    = (float*)A;
  float*  alpha = (float*)Bb;
  float*  mean  = alpha + (size_t)BB*LL;
  float*  sm2   = mean  + (size_t)BB*HH;

  // items -> packed bf16
  k_cvt<<<2048,256,0,stream>>>(items, itbf);

  // CSR build: counts -> rp, then block-level multi-split + bucket sort
  hipMemsetAsync(counts,0,(size_t)NN*4,stream);
  k_count<<<2048,256,0,stream>>>(hrows,counts);
  int nb=(NN+1023)/1024;
  k_scan1<<<nb,1024,0,stream>>>(counts,incl,bsum,NN);
  k_scan2<<<1,64,0,stream>>>(bsum,nb);
  k_scan3<<<(NN+255)/256,256,0,stream>>>(incl,bsum,rp,NN);
  k_binit<<<(NBK+255)/256,256,0,stream>>>(rp,bcur);
  k_msplit<<<MSB,256,0,stream>>>(hrows,hcols,hvals,bcur,bpk);
  k_bucket_sort<<<NBK,256,0,stream>>>(bpk,rp,pk);

  // hypergraph conv
  k_spmm_b    <<<NN/4,256,0,stream>>>(pk,rp, itbf, A);
  k_spmm_b    <<<NN/4,256,0,stream>>>(pk,rp, A,    Bb);
  k_spmm_final<<<NN/4,256,0,stream>>>(pk,rp, A, Bb, items, hgout, hgbf);

  // session attention (MFMA pipeline)
  k_posw1 <<<LL,HH,0,stream>>>(pos_table,w1W,w1b_,posW1);
  k_smean <<<BB,HH,0,stream>>>(hgout,rinfo,slen,mean);
  k_sm2   <<<BB,HH,0,stream>>>(mean,w2W,w2b,sm2);
  k_nsgemm<<<(BB*LL)/64,256,0,stream>>>(hgbf,rinfo,w1W+HH*HH,posW1,ns);
  k_agemm <<<(BB*LL)/64,256,0,stream>>>(ns,w3W,sm2,w3b,fT,alpha);
  k_theta <<<BB,HH,0,stream>>>(ns,alpha,hg_sess);

  // line graph conv
  k_sessline<<<BB,HH,0,stream>>>(items,sinfo,slen,curA,accL);
  for(int s=0;s<3;++s){
    float* srcv=(s&1)?curB:curA;
    float* dstv=(s&1)?curA:curB;
    k_matpart<<<BB,128,0,stream>>>(lineA,srcv,mpart);
    k_matcomb<<<BB*HH/256,256,0,stream>>>(mpart,tmpv,nullptr,0);
    k_matpart<<<BB,128,0,stream>>>(degD,tmpv,mpart);
    k_matcomb<<<BB*HH/256,256,0,stream>>>(mpart,dstv,accL,(s==2)?2:1);
  }

  // SSL loss
  k_ssl<<<BB,HH,0,stream>>>(hg_sess,accL,prow,pcol,lpart);
  k_red<<<1,256,0,stream>>>(lpart,loss);
}

// Round 8
// 777.848 us; speedup vs baseline: 2.0000x; 1.2887x over previous
//
#include <hip/hip_runtime.h>
#include <cstdint>
#include <cstddef>

#define NN   200000
#define HH   128
#define BB   1024
#define LL   50
#define NNZK 3200000
#define RPBK 200      // rows per bucket
#define NBK  1000     // buckets (RPBK*NBK == NN)
#define MSB  256      // multi-split blocks
#define CHUNK (NNZK/MSB)   // 12500 entries per block
#define SK   8        // split-K for line matmuls

typedef unsigned int uint32;
typedef __attribute__((ext_vector_type(8))) short bf16x8;
typedef __attribute__((ext_vector_type(4))) float f32x4;
union U8 { uint32 u[4]; bf16x8 v; };

// ---------- bf16 pack/unpack helpers (RNE) ----------
__device__ __forceinline__ uint32 f2bf2(float a, float b){
  uint32 ua=__float_as_uint(a), ub=__float_as_uint(b);
  ua = (ua + 0x7FFFu + ((ua>>16)&1u)) >> 16;
  ub = (ub + 0x7FFFu + ((ub>>16)&1u)) >> 16;
  return ua | (ub<<16);
}
__device__ __forceinline__ float2 bf2x2f(uint32 u){
  return make_float2(__uint_as_float(u<<16), __uint_as_float(u & 0xFFFF0000u));
}

// ---------- convert items f32 -> packed bf16 ----------
__global__ void k_cvt(const float* __restrict__ x, uint32* __restrict__ o){
  const int n = NN*64;
  for(int i=blockIdx.x*blockDim.x+threadIdx.x; i<n; i+=gridDim.x*blockDim.x){
    float2 v = ((const float2*)x)[i];
    o[i] = f2bf2(v.x, v.y);
  }
}

// ---------------- bucket histogram (LDS-staged, 256K global atomics) ----------------
__global__ __launch_bounds__(256) void k_bhist(const int* __restrict__ rows, int* __restrict__ bhist){
  __shared__ int h[NBK];
  for(int b=threadIdx.x;b<NBK;b+=256) h[b]=0;
  __syncthreads();
  const int i0=blockIdx.x*CHUNK;
  for(int i=i0+threadIdx.x;i<i0+CHUNK;i+=256) atomicAdd(&h[rows[i]/RPBK],1);
  __syncthreads();
  for(int b=threadIdx.x;b<NBK;b+=256){ int c=h[b]; if(c) atomicAdd(&bhist[b],c); }
}

__global__ __launch_bounds__(1024) void k_bscan(const int* __restrict__ bhist, int* __restrict__ bstart){
  __shared__ int s[1024];
  int t=threadIdx.x;
  int v=(t<NBK)?bhist[t]:0;
  s[t]=v;
  __syncthreads();
  for(int off=1;off<1024;off<<=1){
    int u=(t>=off)?s[t-off]:0; __syncthreads(); s[t]+=u; __syncthreads();
  }
  if(t<NBK) bstart[t]=s[t]-v;   // exclusive prefix
}

__global__ void k_binit(const int* __restrict__ bstart, int* __restrict__ bcur){
  int i=blockIdx.x*blockDim.x+threadIdx.x;
  if(i<NBK) bcur[i]=bstart[i];
}

// two-pass per block: LDS histogram -> one global atomic per (block,bucket) -> ranged writes
__global__ __launch_bounds__(256) void k_msplit(const int* __restrict__ rows,
    const int* __restrict__ cols, const float* __restrict__ vals,
    int* __restrict__ bcur, int2* __restrict__ bpk){
  __shared__ int hist[NBK];
  __shared__ int rbase[NBK];
  const int tid=threadIdx.x;
  const int i0=blockIdx.x*CHUNK, i1=i0+CHUNK;
  for(int b=tid;b<NBK;b+=256) hist[b]=0;
  __syncthreads();
  for(int i=i0+tid;i<i1;i+=256) atomicAdd(&hist[rows[i]/RPBK],1);
  __syncthreads();
  for(int b=tid;b<NBK;b+=256){
    int c=hist[b];
    rbase[b] = c ? atomicAdd(&bcur[b],c) : 0;
  }
  __syncthreads();
  for(int b=tid;b<NBK;b+=256) hist[b]=0;
  __syncthreads();
  for(int i=i0+tid;i<i1;i+=256){
    int r=rows[i];
    int b=r/RPBK, ro=r-b*RPBK;
    int p = rbase[b] + atomicAdd(&hist[b],1);
    bpk[p]=make_int2(cols[i] | (ro<<18), __float_as_int(vals[i]));
  }
}

// pass 2: per-bucket row-sort; derives per-row offsets (writes rp) via LDS hist+scan
__global__ __launch_bounds__(256) void k_bucket_sort(const int2* __restrict__ bpk,
    const int* __restrict__ bstart, const int* __restrict__ bhist,
    int2* __restrict__ pk, int* __restrict__ rp){
  __shared__ int cnt[RPBK];
  __shared__ int sc[256];
  int b=blockIdx.x, t=threadIdx.x;
  int base=bstart[b], total=bhist[b];
  if(t<RPBK) cnt[t]=0;
  __syncthreads();
  for(int j=t;j<total;j+=256) atomicAdd(&cnt[((uint32)bpk[base+j].x)>>18],1);
  __syncthreads();
  int myc=(t<RPBK)?cnt[t]:0;
  sc[t]=myc;
  __syncthreads();
  for(int off=1;off<256;off<<=1){
    int u=(t>=off)?sc[t-off]:0; __syncthreads(); sc[t]+=u; __syncthreads();
  }
  int excl = sc[t]-myc;
  __syncthreads();
  if(t<RPBK){ cnt[t]=base+excl; rp[b*RPBK+t]=base+excl; }
  if(b==0 && t==0) rp[NN]=NNZK;
  __syncthreads();
  for(int j=t;j<total;j+=256){
    int2 e=bpk[base+j];
    int ro=((uint32)e.x)>>18;
    int p=atomicAdd(&cnt[ro],1);
    pk[p]=make_int2(e.x&0x3FFFF, e.y);
  }
}

// ---------------- SpMM steps (bf16 src, one wave per row, 8x unrolled) ----------------
__device__ __forceinline__ void spmm_body(const int2* __restrict__ pk, int j0, int j1,
    const uint32* __restrict__ src, int lane, float& ax, float& ay){
  int j=j0;
  for(; j+8<=j1; j+=8){
    int2 p0=pk[j],   p1=pk[j+1], p2=pk[j+2], p3=pk[j+3];
    int2 p4=pk[j+4], p5=pk[j+5], p6=pk[j+6], p7=pk[j+7];
    uint32 e0=src[(size_t)p0.x*64+lane], e1=src[(size_t)p1.x*64+lane];
    uint32 e2=src[(size_t)p2.x*64+lane], e3=src[(size_t)p3.x*64+lane];
    uint32 e4=src[(size_t)p4.x*64+lane], e5=src[(size_t)p5.x*64+lane];
    uint32 e6=src[(size_t)p6.x*64+lane], e7=src[(size_t)p7.x*64+lane];
    float2 f0=bf2x2f(e0), f1=bf2x2f(e1), f2=bf2x2f(e2), f3=bf2x2f(e3);
    float2 f4=bf2x2f(e4), f5=bf2x2f(e5), f6=bf2x2f(e6), f7=bf2x2f(e7);
    float v0=__int_as_float(p0.y), v1=__int_as_float(p1.y);
    float v2=__int_as_float(p2.y), v3=__int_as_float(p3.y);
    float v4=__int_as_float(p4.y), v5=__int_as_float(p5.y);
    float v6=__int_as_float(p6.y), v7=__int_as_float(p7.y);
    ax=fmaf(v0,f0.x,ax); ay=fmaf(v0,f0.y,ay);
    ax=fmaf(v1,f1.x,ax); ay=fmaf(v1,f1.y,ay);
    ax=fmaf(v2,f2.x,ax); ay=fmaf(v2,f2.y,ay);
    ax=fmaf(v3,f3.x,ax); ay=fmaf(v3,f3.y,ay);
    ax=fmaf(v4,f4.x,ax); ay=fmaf(v4,f4.y,ay);
    ax=fmaf(v5,f5.x,ax); ay=fmaf(v5,f5.y,ay);
    ax=fmaf(v6,f6.x,ax); ay=fmaf(v6,f6.y,ay);
    ax=fmaf(v7,f7.x,ax); ay=fmaf(v7,f7.y,ay);
  }
  for(; j+4<=j1; j+=4){
    int2 p0=pk[j], p1=pk[j+1], p2=pk[j+2], p3=pk[j+3];
    uint32 e0=src[(size_t)p0.x*64+lane], e1=src[(size_t)p1.x*64+lane];
    uint32 e2=src[(size_t)p2.x*64+lane], e3=src[(size_t)p3.x*64+lane];
    float2 f0=bf2x2f(e0), f1=bf2x2f(e1), f2=bf2x2f(e2), f3=bf2x2f(e3);
    float v0=__int_as_float(p0.y), v1=__int_as_float(p1.y);
    float v2=__int_as_float(p2.y), v3=__int_as_float(p3.y);
    ax=fmaf(v0,f0.x,ax); ay=fmaf(v0,f0.y,ay);
    ax=fmaf(v1,f1.x,ax); ay=fmaf(v1,f1.y,ay);
    ax=fmaf(v2,f2.x,ax); ay=fmaf(v2,f2.y,ay);
    ax=fmaf(v3,f3.x,ax); ay=fmaf(v3,f3.y,ay);
  }
  for(; j<j1; ++j){
    int2 p=pk[j];
    float2 f=bf2x2f(src[(size_t)p.x*64+lane]);
    float v=__int_as_float(p.y);
    ax=fmaf(v,f.x,ax); ay=fmaf(v,f.y,ay);
  }
}

__global__ __launch_bounds__(256) void k_spmm_b(
    const int2* __restrict__ pk, const int* __restrict__ rp,
    const uint32* __restrict__ src, uint32* __restrict__ dst)
{
  int wid = blockIdx.x*4 + (threadIdx.x>>6);
  int lane = threadIdx.x & 63;
  if(wid>=NN) return;
  float ax=0.f, ay=0.f;
  spmm_body(pk, rp[wid], rp[wid+1], src, lane, ax, ay);
  dst[(size_t)wid*64+lane]=f2bf2(ax,ay);
}

// final: e3 = A@B ; acc=(xbf+e1+e2+e3)*0.25 -> hgout(f32, 4B-aligned) + hgbf(packed bf16)
// NOTE: xbf aliases obf (itbf) — read/write same element by same thread only.
__global__ __launch_bounds__(256) void k_spmm_final(
    const int2* __restrict__ pk, const int* __restrict__ rp,
    const uint32* __restrict__ Abuf, const uint32* __restrict__ Bbuf,
    const uint32* xbf, float* __restrict__ acc, uint32* obf)
{
  int wid = blockIdx.x*4 + (threadIdx.x>>6);
  int lane = threadIdx.x & 63;
  if(wid>=NN) return;
  float ax=0.f, ay=0.f;
  spmm_body(pk, rp[wid], rp[wid+1], Bbuf, lane, ax, ay);
  float2 xv  = bf2x2f(xbf [(size_t)wid*64+lane]);
  float2 e1v = bf2x2f(Abuf[(size_t)wid*64+lane]);
  float2 e2v = bf2x2f(Bbuf[(size_t)wid*64+lane]);
  size_t ao=(size_t)wid*128 + lane*2;
  float rx = (xv.x + e1v.x + e2v.x + ax)*0.25f;
  float ry = (xv.y + e1v.y + e2v.y + ay)*0.25f;
  acc[ao]=rx; acc[ao+1]=ry;
  obf[(size_t)wid*64+lane]=f2bf2(rx,ry);
}

// ---------------- posW1[l][h] = pos_table[l]@w1_W[:128] + w1_b ----------------
__global__ __launch_bounds__(128) void k_posw1(const float* __restrict__ pos_table,
    const float* __restrict__ w1W, const float* __restrict__ w1b, float* __restrict__ posW1){
  int l=blockIdx.x, h=threadIdx.x;
  float a=w1b[h];
  for(int k=0;k<HH;++k) a = fmaf(pos_table[l*HH+k], w1W[k*HH+h], a);
  posW1[l*HH+h]=a;
}

// ---------------- MFMA GEMM 1: ns = tanh(posW1[l] + gather(hgbf) @ w1seq) ----------------
#define AS 69
#define BS 67
__global__ __launch_bounds__(256) void k_nsgemm(
    const uint32* __restrict__ hgbf, const int* __restrict__ rev,
    const float* __restrict__ w1b, const float* __restrict__ posW1,
    float* __restrict__ ns)
{
  __shared__ uint32 sA[64*AS];
  __shared__ uint32 sB[128*BS];
  const int tid=threadIdx.x;
  {
    int r=tid>>2, p=tid&3;
    int idx = rev[blockIdx.x*64 + r];
    if(idx>0 && idx<=NN){
      const uint32* s = hgbf + (size_t)(idx-1)*64 + p*16;
      #pragma unroll
      for(int j=0;j<16;++j) sA[r*AS+p*16+j]=s[j];
    } else {
      #pragma unroll
      for(int j=0;j<16;++j) sA[r*AS+p*16+j]=0u;
    }
  }
  for(int i=tid;i<128*64;i+=256){
    int n=i&127, kp=i>>7;
    sB[n*BS+kp]=f2bf2(w1b[(2*kp)*HH+n], w1b[(2*kp+1)*HH+n]);
  }
  __syncthreads();
  const int w=tid>>6, lane=tid&63, g=lane>>4, m15=lane&15;
  f32x4 acc[8];
  #pragma unroll
  for(int nt=0;nt<8;++nt) acc[nt]=(f32x4){0.f,0.f,0.f,0.f};
  #pragma unroll
  for(int kt=0;kt<4;++kt){
    U8 a;
    int ab=(w*16+m15)*AS + kt*16 + g*4;
    a.u[0]=sA[ab]; a.u[1]=sA[ab+1]; a.u[2]=sA[ab+2]; a.u[3]=sA[ab+3];
    #pragma unroll
    for(int nt=0;nt<8;++nt){
      U8 b;
      int bb=(nt*16+m15)*BS + kt*16 + g*4;
      b.u[0]=sB[bb]; b.u[1]=sB[bb+1]; b.u[2]=sB[bb+2]; b.u[3]=sB[bb+3];
      acc[nt]=__builtin_amdgcn_mfma_f32_16x16x32_bf16(a.v,b.v,acc[nt],0,0,0);
    }
  }
  int rowbase = blockIdx.x*64 + w*16 + g*4;
  #pragma unroll
  for(int r=0;r<4;++r){
    int gr=rowbase+r;
    int l=gr%LL;
    #pragma unroll
    for(int nt=0;nt<8;++nt){
      int col=nt*16+m15;
      ns[(size_t)gr*HH+col] = tanhf(acc[nt][r] + posW1[l*HH+col]);
    }
  }
}

// ---------------- MFMA GEMM 2: alpha = sum_h sigmoid(sm2[b]+ns@w3+b3)*fT ----------------
__global__ __launch_bounds__(256) void k_agemm(
    const float* __restrict__ ns, const float* __restrict__ w3,
    const float* __restrict__ sm2, const float* __restrict__ b3,
    const float* __restrict__ fT, float* __restrict__ alpha)
{
  __shared__ uint32 sA[64*AS];
  __shared__ uint32 sB[128*BS];
  const int tid=threadIdx.x;
  {
    int r=tid>>2, p=tid&3;
    const float2* s = (const float2*)(ns + (size_t)(blockIdx.x*64+r)*HH + p*32);
    #pragma unroll
    for(int j=0;j<16;++j){ float2 f=s[j]; sA[r*AS+p*16+j]=f2bf2(f.x,f.y); }
  }
  for(int i=tid;i<128*64;i+=256){
    int n=i&127, kp=i>>7;
    sB[n*BS+kp]=f2bf2(w3[(2*kp)*HH+n], w3[(2*kp+1)*HH+n]);
  }
  __syncthreads();
  const int w=tid>>6, lane=tid&63, g=lane>>4, m15=lane&15;
  f32x4 acc[8];
  #pragma unroll
  for(int nt=0;nt<8;++nt) acc[nt]=(f32x4){0.f,0.f,0.f,0.f};
  #pragma unroll
  for(int kt=0;kt<4;++kt){
    U8 a;
    int ab=(w*16+m15)*AS + kt*16 + g*4;
    a.u[0]=sA[ab]; a.u[1]=sA[ab+1]; a.u[2]=sA[ab+2]; a.u[3]=sA[ab+3];
    #pragma unroll
    for(int nt=0;nt<8;++nt){
      U8 b;
      int bb=(nt*16+m15)*BS + kt*16 + g*4;
      b.u[0]=sB[bb]; b.u[1]=sB[bb+1]; b.u[2]=sB[bb+2]; b.u[3]=sB[bb+3];
      acc[nt]=__builtin_amdgcn_mfma_f32_16x16x32_bf16(a.v,b.v,acc[nt],0,0,0);
    }
  }
  int rowbase = blockIdx.x*64 + w*16 + g*4;
  #pragma unroll
  for(int r=0;r<4;++r){
    int gr=rowbase+r;
    int b_=gr/LL;
    float rsum=0.f;
    #pragma unroll
    for(int nt=0;nt<8;++nt){
      int col=nt*16+m15;
      float gv = acc[nt][r] + sm2[b_*HH+col] + b3[col];
      rsum += fT[col] / (1.f + expf(-gv));
    }
    rsum += __shfl_xor(rsum,1);
    rsum += __shfl_xor(rsum,2);
    rsum += __shfl_xor(rsum,4);
    rsum += __shfl_xor(rsum,8);
    if(m15==0) alpha[gr]=rsum;
  }
}

// ---------------- sess_mean (bf16 gather) + sm2 ----------------
__global__ __launch_bounds__(128) void k_smean(const uint32* __restrict__ hgbf,
    const int* __restrict__ rev, const int* __restrict__ slen, float* __restrict__ mean){
  int b=blockIdx.x, h=threadIdx.x;
  int hw=h>>1, hi=h&1;
  float s=0.f;
  for(int l=0;l<LL;++l){
    int idx=rev[b*LL+l];
    if(idx>0 && idx<=NN){
      float2 f=bf2x2f(hgbf[(size_t)(idx-1)*64+hw]);
      s += hi ? f.y : f.x;
    }
  }
  mean[b*HH+h]=s/(float)slen[b];
}

__global__ __launch_bounds__(128) void k_sm2(const float* __restrict__ mean,
    const float* __restrict__ w2, const float* __restrict__ b2, float* __restrict__ sm2){
  __shared__ float sm[HH];
  int b=blockIdx.x, h=threadIdx.x;
  sm[h]=mean[b*HH+h]; __syncthreads();
  float a=b2[h];
  for(int k=0;k<HH;++k) a=fmaf(sm[k], w2[k*HH+h], a);
  sm2[b*HH+h]=a;
}

// ---------------- theta ----------------
__global__ __launch_bounds__(128) void k_theta(const float* __restrict__ ns,
    const float* __restrict__ alpha, float* __restrict__ hg_sess){
  __shared__ float sal[64];
  int b=blockIdx.x, h=threadIdx.x;
  if(h<LL) sal[h]=alpha[b*LL+h];
  __syncthreads();
  float t=0.f;
  for(int l=0;l<LL;++l) t=fmaf(sal[l], ns[((size_t)b*LL+l)*HH+h], t);
  hg_sess[(size_t)b*HH+h]=t;
}

// ---------------- line graph ----------------
__global__ __launch_bounds__(128) void k_sessline(const float* __restrict__ items,
    const int* __restrict__ sinfo, const int* __restrict__ slen,
    float* __restrict__ cur, float* __restrict__ acc){
  int b=blockIdx.x, h=threadIdx.x;
  float s=0.f;
  for(int l=0;l<LL;++l){
    int idx=sinfo[b*LL+l];
    if(idx>0 && idx<=NN) s += items[(size_t)(idx-1)*HH+h];
  }
  s /= (float)slen[b];
  cur[(size_t)b*HH+h]=s; acc[(size_t)b*HH+h]=s;
}

// part[kc] = M[:,kc*128:+128] @ src[kc*128:+128,:]  (SK=8)
__global__ __launch_bounds__(128) void k_matpart(const float* __restrict__ M,
    const float* __restrict__ src, float* __restrict__ part){
  int rq = blockIdx.x >> 3;
  int kc = blockIdx.x & 7;
  int h = threadIdx.x;
  int r0 = rq*4;
  const int KC = BB/SK;
  const float* m0 = M + (size_t)r0*BB + kc*KC;
  const float* m1 = m0 + BB;
  const float* m2 = m1 + BB;
  const float* m3 = m2 + BB;
  const float* s0 = src + (size_t)kc*KC*HH + h;
  float a0=0,a1=0,a2=0,a3=0;
  for(int k=0;k<KC;++k){
    float s=s0[(size_t)k*HH];
    a0=fmaf(m0[k],s,a0); a1=fmaf(m1[k],s,a1);
    a2=fmaf(m2[k],s,a2); a3=fmaf(m3[k],s,a3);
  }
  size_t o=(size_t)kc*BB*HH + (size_t)r0*HH + h;
  part[o]=a0; part[o+HH]=a1; part[o+2*HH]=a2; part[o+3*HH]=a3;
}

__global__ __launch_bounds__(256) void k_matcomb(const float* __restrict__ part,
    float* __restrict__ dst, float* __restrict__ acc, int mode){
  int i = blockIdx.x*256+threadIdx.x;
  const int S = BB*HH;
  float v = 0.f;
  #pragma unroll
  for(int kc=0;kc<SK;++kc) v += part[i+(size_t)kc*S];
  dst[i]=v;
  if(mode==1) acc[i]+=v;
  else if(mode==2) acc[i]=(acc[i]+v)*0.25f;
}

// ---------------- SSL loss (deterministic two-stage) ----------------
__global__ __launch_bounds__(128) void k_ssl(const float* __restrict__ hg,
    const float* __restrict__ line, const int* __restrict__ pr,
    const int* __restrict__ pc, float* __restrict__ part){
  int b=blockIdx.x, h=threadIdx.x;
  __shared__ float sp[2][2];
  float lv = line[(size_t)b*HH+h];
  float v1 = hg[(size_t)b*HH+h]*lv;
  float v2 = hg[(size_t)pr[b]*HH + pc[h]]*lv;
  for(int o=32;o>0;o>>=1){ v1+=__shfl_xor(v1,o); v2+=__shfl_xor(v2,o); }
  int wv=h>>6, ln=h&63;
  if(ln==0){ sp[0][wv]=v1; sp[1][wv]=v2; }
  __syncthreads();
  if(h==0){
    float pos=sp[0][0]+sp[0][1];
    float neg=sp[1][0]+sp[1][1];
    float sigp=1.f/(1.f+expf(-pos));
    float sign_=1.f/(1.f+expf(-neg));
    part[b] = -logf(1e-8f+sigp) - logf(1e-8f+(1.f-sign_));
  }
}

__global__ __launch_bounds__(256) void k_red(const float* __restrict__ part, float* __restrict__ loss){
  __shared__ float s[256];
  int t=threadIdx.x;
  s[t]=part[t]+part[t+256]+part[t+512]+part[t+768];
  __syncthreads();
  for(int o=128;o>0;o>>=1){ if(t<o) s[t]+=s[t+o]; __syncthreads(); }
  if(t==0) *loss = 0.01f*s[0];
}

extern "C" void kernel_launch(void* const* d_in, const int* in_sizes, int n_in,
                              void* d_out, int out_size, void* d_ws, size_t ws_size,
                              hipStream_t stream){
  const float* items    =(const float*)d_in[0];
  const float* pos_table=(const float*)d_in[1];
  const float* w1W      =(const float*)d_in[2];
  const float* w1b_     =(const float*)d_in[3];
  const float* w2W      =(const float*)d_in[4];
  const float* w2b      =(const float*)d_in[5];
  const float* w3W      =(const float*)d_in[6];
  const float* w3b      =(const float*)d_in[7];
  const float* fT       =(const float*)d_in[8];
  const float* hvals    =(const float*)d_in[9];
  const float* lineA    =(const float*)d_in[10];
  const float* degD     =(const float*)d_in[11];
  const int*   hrows    =(const int*)d_in[12];
  const int*   hcols    =(const int*)d_in[13];
  const int*   sinfo    =(const int*)d_in[14];   // int64 in ref -> int32 in harness
  const int*   rinfo    =(const int*)d_in[15];
  const int*   slen     =(const int*)d_in[16];
  const int*   prow     =(const int*)d_in[18];
  const int*   pcol     =(const int*)d_in[19];

  float* outf   = (float*)d_out;
  float* hg_sess= outf;
  float* loss   = outf + (size_t)BB*HH;
  float* hgout  = outf + (size_t)BB*HH + 1;    // hg_item (4B-aligned only)

  char* base=(char*)d_ws; size_t off=0;
  auto carve=[&](size_t bytes)->char*{ char* p=base+off; off=(off+bytes+255)&~(size_t)255; return p; };

  float*  posW1 =(float*) carve((size_t)LL*HH*4);
  float*  curA  =(float*) carve((size_t)BB*HH*4);
  float*  curB  =(float*) carve((size_t)BB*HH*4);
  float*  tmpv  =(float*) carve((size_t)BB*HH*4);
  float*  accL  =(float*) carve((size_t)BB*HH*4);
  float*  lpart =(float*) carve((size_t)BB*4);
  float*  mpart =(float*) carve((size_t)SK*BB*HH*4);
  int2*   pk    =(int2*)  carve((size_t)NNZK*8);
  int*    rp    =(int*)   carve((size_t)(NN+1)*4);
  int*    bhist =(int*)   carve((size_t)NBK*4);
  int*    bstart=(int*)   carve((size_t)NBK*4);
  int*    bcur  =(int*)   carve((size_t)NBK*4);
  uint32* itbf  =(uint32*)carve((size_t)NN*64*4);
  uint32* A     =(uint32*)carve((size_t)NN*64*4);
  uint32* Bb    =(uint32*)carve((size_t)NN*64*4);
  if(off > ws_size) return;

  // overlays: bpk lives in A's region during CSR build (A written later);
  // after k_spmm_final: itbf -> hgbf, A -> ns, Bb -> alpha/mean/sm2
  int2*   bpk   = (int2*)A;
  uint32* hgbf  = itbf;
  float*  ns    = (float*)A;
  float*  alpha = (float*)Bb;
  float*  mean  = alpha + (size_t)BB*LL;
  float*  sm2   = mean  + (size_t)BB*HH;

  // items -> packed bf16
  k_cvt<<<2048,256,0,stream>>>(items, itbf);

  // CSR build: bucket hist/scan -> multi-split -> bucket sort (writes rp too)
  hipMemsetAsync(bhist,0,(size_t)NBK*4,stream);
  k_bhist<<<MSB,256,0,stream>>>(hrows,bhist);
  k_bscan<<<1,1024,0,stream>>>(bhist,bstart);
  k_binit<<<(NBK+255)/256,256,0,stream>>>(bstart,bcur);
  k_msplit<<<MSB,256,0,stream>>>(hrows,hcols,hvals,bcur,bpk);
  k_bucket_sort<<<NBK,256,0,stream>>>(bpk,bstart,bhist,pk,rp);

  // hypergraph conv
  k_spmm_b    <<<NN/4,256,0,stream>>>(pk,rp, itbf, A);
  k_spmm_b    <<<NN/4,256,0,stream>>>(pk,rp, A,    Bb);
  k_spmm_final<<<NN/4,256,0,stream>>>(pk,rp, A, Bb, itbf, hgout, hgbf);

  // session attention (MFMA pipeline)
  k_posw1 <<<LL,HH,0,stream>>>(pos_table,w1W,w1b_,posW1);
  k_smean <<<BB,HH,0,stream>>>(hgbf,rinfo,slen,mean);
  k_sm2   <<<BB,HH,0,stream>>>(mean,w2W,w2b,sm2);
  k_nsgemm<<<(BB*LL)/64,256,0,stream>>>(hgbf,rinfo,w1W+HH*HH,posW1,ns);
  k_agemm <<<(BB*LL)/64,256,0,stream>>>(ns,w3W,sm2,w3b,fT,alpha);
  k_theta <<<BB,HH,0,stream>>>(ns,alpha,hg_sess);

  // line graph conv
  k_sessline<<<BB,HH,0,stream>>>(items,sinfo,slen,curA,accL);
  for(int s=0;s<3;++s){
    float* srcv=(s&1)?curB:curA;
    float* dstv=(s&1)?curA:curB;
    k_matpart<<<(BB/4)*SK,128,0,stream>>>(lineA,srcv,mpart);
    k_matcomb<<<BB*HH/256,256,0,stream>>>(mpart,tmpv,nullptr,0);
    k_matpart<<<(BB/4)*SK,128,0,stream>>>(degD,tmpv,mpart);
    k_matcomb<<<BB*HH/256,256,0,stream>>>(mpart,dstv,accL,(s==2)?2:1);
  }

  // SSL loss
  k_ssl<<<BB,HH,0,stream>>>(hg_sess,accL,prow,pcol,lpart);
  k_red<<<1,256,0,stream>>>(lpart,loss);
}